// Round 3
// baseline (401.195 us; speedup 1.0000x reference)
//
#include <hip/hip_runtime.h>
#include <math.h>

#define NB 16
#define NN 16384
#define DD 128
#define KK 10

// ws layout (floats):
//   hsum : [2][NB][DD]      @0      4096   (plane 0 = sum over H1 rows, plane 1 = H2)
//   v    : [2][NB][KK][DD]  @4096   40960  (scale folded in: 1/(N*sqrt(d)))
//   accg : [2][NB][40]      @45056  1280   ([k]=SE, [10+k]=Yx, [20+k]=Yy, [30+k]=Yz)
#define WS_FLOATS 46336

typedef float f4v __attribute__((ext_vector_type(4)));
__device__ __forceinline__ float4 ntload4(const float* p) {
    f4v t = __builtin_nontemporal_load((const f4v*)p);
    return make_float4(t.x, t.y, t.z, t.w);
}

// ---------------------------------------------------------------------------
// Kernel 1: column sums of H2 only (H1's sums come fused from the score pass).
// grid 1024 x 256; 2 grid-strided tiles of 128 rows per block (sliding window).
__global__ __launch_bounds__(256) void k_mean2(const float* __restrict__ H2,
                                               float* __restrict__ hsum) {
    int tid = threadIdx.x;
    __shared__ float red[4][32][4];
    for (int it = 0; it < 2; ++it) {
        int tau = blockIdx.x + it * 1024;     // 0..2047 tiles, contiguous in memory
        int b = tau >> 7;
        const float4* src4 = (const float4*)(H2 + (size_t)tau * (128 * DD));
        float4 x[16];
#pragma unroll
        for (int i = 0; i < 16; ++i)
            x[i] = src4[i * 256 + tid];
        float4 s = make_float4(0.f, 0.f, 0.f, 0.f);
#pragma unroll
        for (int i = 0; i < 16; ++i) {
            s.x += x[i].x; s.y += x[i].y; s.z += x[i].z; s.w += x[i].w;
        }
        s.x += __shfl_xor(s.x, 32);
        s.y += __shfl_xor(s.y, 32);
        s.z += __shfl_xor(s.z, 32);
        s.w += __shfl_xor(s.w, 32);
        int wave = tid >> 6, lane = tid & 63;
        if (lane < 32) {
            red[wave][lane][0] = s.x; red[wave][lane][1] = s.y;
            red[wave][lane][2] = s.z; red[wave][lane][3] = s.w;
        }
        __syncthreads();
        if (tid < 32) {
            float t0 = 0.f, t1 = 0.f, t2 = 0.f, t3 = 0.f;
#pragma unroll
            for (int w = 0; w < 4; ++w) {
                t0 += red[w][tid][0]; t1 += red[w][tid][1];
                t2 += red[w][tid][2]; t3 += red[w][tid][3];
            }
            float* dst = hsum + (size_t)(NB + b) * DD + tid * 4;  // plane 1 (H2)
            atomicAdd(dst + 0, t0);
            atomicAdd(dst + 1, t1);
            atomicAdd(dst + 2, t2);
            atomicAdd(dst + 3, t3);
        }
        __syncthreads();   // protect red before next tile overwrites
    }
}

// ---------------------------------------------------------------------------
// Kernel 2: v[p][b][k][d] = scale * sum_e W[k][d][e] * hsum[1-p][b][e]
// grid 160 = 16 x 10, 128 threads; p is a launch parameter.
__global__ __launch_bounds__(128) void k_v(const float* __restrict__ W1,
                                           const float* __restrict__ W2,
                                           const float* __restrict__ hsum,
                                           float* __restrict__ v, int p) {
    int bi = blockIdx.x;
    int b = bi / 10;
    int k = bi % 10;
    const float* W = (p ? W2 : W1) + (size_t)k * DD * DD;
    const float* hb = hsum + (size_t)((1 - p) * NB + b) * DD;
    __shared__ float4 h_s[32];
    int tid = threadIdx.x;
    if (tid < 32) h_s[tid] = ((const float4*)hb)[tid];
    __syncthreads();
    const float4* Wrow = (const float4*)(W + (size_t)tid * DD);
    float acc = 0.f;
#pragma unroll 8
    for (int e4 = 0; e4 < 32; ++e4) {
        float4 w4 = Wrow[e4];
        float4 h4 = h_s[e4];
        acc += w4.x * h4.x + w4.y * h4.y + w4.z * h4.z + w4.w * h4.w;
    }
    const float SCALE = (float)(1.0 / (16384.0 * 11.313708498984761));  // 1/(N*sqrt(128))
    v[((size_t)(p * NB + b) * KK + k) * DD + tid] = acc * SCALE;
}

// ---------------------------------------------------------------------------
// Kernel 3: fused score pass. Computes exp-scores + weighted-X partial sums,
// and (optionally) the column sums of H in the same read.
// grid 512 x 256; 4 grid-strided tiles of 128 rows (sliding ~32 MB window).
// H loads are nontemporal: H1 is read exactly once overall; the final H2 pass
// is H2's last use — keeps the other tensor resident in L3.
__global__ __launch_bounds__(256) void k_pass(const float* __restrict__ H,
                                              const float* __restrict__ X,
                                              const float* __restrict__ v,
                                              float* __restrict__ accg,
                                              float* __restrict__ hsumout,
                                              int do_sum) {
    __shared__ float4 v_s4[KK * DD / 4];   // 1280 floats
    __shared__ float red[4][40];
    __shared__ float4 sred[4][4][8];       // [wave][j][l]
    float* v_s = (float*)v_s4;

    int tid = threadIdx.x;
    int g = tid >> 3;       // lane-group 0..31 (8 per wave)
    int l = tid & 7;        // lane within group -> d-slice

    for (int it = 0; it < 4; ++it) {
        int tau = blockIdx.x + it * 512;    // 0..2047 tiles, contiguous in memory
        int b = tau >> 7;
        const float* Hb = H + (size_t)tau * (128 * DD);
        const float* Xb = X + ((size_t)b * NN + (size_t)(tau & 127) * 128) * 3;
        const float* vp = v + (size_t)b * KK * DD;
        int nb = g << 2;

        // ---- issue ALL global loads first ----
        float4 h[4][4];     // [j][r]
#pragma unroll
        for (int j = 0; j < 4; ++j)
#pragma unroll
            for (int r = 0; r < 4; ++r)
                h[j][r] = ntload4(Hb + (size_t)(nb + r) * DD + (j << 5) + (l << 2));
        float xv[4][3];
#pragma unroll
        for (int r = 0; r < 4; ++r) {
            const float* xr = Xb + (size_t)(nb + r) * 3;
            xv[r][0] = xr[0]; xv[r][1] = xr[1]; xv[r][2] = xr[2];
        }

        __syncthreads();    // prev-iter consumers of v_s/red/sred done
        for (int i = tid; i < KK * DD / 4; i += 256)
            v_s4[i] = ((const float4*)vp)[i];
        __syncthreads();    // v_s ready

        float accs[4][KK];
#pragma unroll
        for (int r = 0; r < 4; ++r)
#pragma unroll
            for (int k = 0; k < KK; ++k) accs[r][k] = 0.f;

#pragma unroll
        for (int j = 0; j < 4; ++j) {
#pragma unroll
            for (int k = 0; k < KK; ++k) {
                float4 vv = *(const float4*)(v_s + k * DD + (j << 5) + (l << 2));
#pragma unroll
                for (int r = 0; r < 4; ++r)
                    accs[r][k] += h[j][r].x * vv.x + h[j][r].y * vv.y +
                                  h[j][r].z * vv.z + h[j][r].w * vv.w;
            }
        }
        // reduce d-partials across the 8 lanes of the group
#pragma unroll
        for (int r = 0; r < 4; ++r)
#pragma unroll
            for (int k = 0; k < KK; ++k) {
                float s = accs[r][k];
                s += __shfl_xor(s, 1);
                s += __shfl_xor(s, 2);
                s += __shfl_xor(s, 4);
                accs[r][k] = s;
            }

        float pSE[KK], pY0[KK], pY1[KK], pY2[KK];
#pragma unroll
        for (int k = 0; k < KK; ++k) { pSE[k] = 0.f; pY0[k] = 0.f; pY1[k] = 0.f; pY2[k] = 0.f; }

        // |s| <~ 0.3, exp without max-subtraction is exact softmax semantics.
#pragma unroll
        for (int r = 0; r < 4; ++r) {
            float x0 = xv[r][0], x1 = xv[r][1], x2 = xv[r][2];
#pragma unroll
            for (int k = 0; k < KK; ++k) {
                float e = __expf(accs[r][k]);
                pSE[k] += e;
                pY0[k] += e * x0;
                pY1[k] += e * x1;
                pY2[k] += e * x2;
            }
        }
#pragma unroll
        for (int k = 0; k < KK; ++k) {
            pSE[k] += __shfl_xor(pSE[k], 8);  pSE[k] += __shfl_xor(pSE[k], 16);  pSE[k] += __shfl_xor(pSE[k], 32);
            pY0[k] += __shfl_xor(pY0[k], 8);  pY0[k] += __shfl_xor(pY0[k], 16);  pY0[k] += __shfl_xor(pY0[k], 32);
            pY1[k] += __shfl_xor(pY1[k], 8);  pY1[k] += __shfl_xor(pY1[k], 16);  pY1[k] += __shfl_xor(pY1[k], 32);
            pY2[k] += __shfl_xor(pY2[k], 8);  pY2[k] += __shfl_xor(pY2[k], 16);  pY2[k] += __shfl_xor(pY2[k], 32);
        }
        int wave = tid >> 6, lane = tid & 63;
        if (lane == 0) {
#pragma unroll
            for (int k = 0; k < KK; ++k) {
                red[wave][k] = pSE[k];
                red[wave][10 + k] = pY0[k];
                red[wave][20 + k] = pY1[k];
                red[wave][30 + k] = pY2[k];
            }
        }
        if (do_sum) {
            // per-thread column sums over its 4 rows; cols (j*32 + l*4 .. +3)
            float4 cs[4];
#pragma unroll
            for (int j = 0; j < 4; ++j) {
                cs[j].x = h[j][0].x + h[j][1].x + h[j][2].x + h[j][3].x;
                cs[j].y = h[j][0].y + h[j][1].y + h[j][2].y + h[j][3].y;
                cs[j].z = h[j][0].z + h[j][1].z + h[j][2].z + h[j][3].z;
                cs[j].w = h[j][0].w + h[j][1].w + h[j][2].w + h[j][3].w;
            }
#pragma unroll
            for (int j = 0; j < 4; ++j) {
                cs[j].x += __shfl_xor(cs[j].x, 8); cs[j].x += __shfl_xor(cs[j].x, 16); cs[j].x += __shfl_xor(cs[j].x, 32);
                cs[j].y += __shfl_xor(cs[j].y, 8); cs[j].y += __shfl_xor(cs[j].y, 16); cs[j].y += __shfl_xor(cs[j].y, 32);
                cs[j].z += __shfl_xor(cs[j].z, 8); cs[j].z += __shfl_xor(cs[j].z, 16); cs[j].z += __shfl_xor(cs[j].z, 32);
                cs[j].w += __shfl_xor(cs[j].w, 8); cs[j].w += __shfl_xor(cs[j].w, 16); cs[j].w += __shfl_xor(cs[j].w, 32);
            }
            if (lane < 8) {
#pragma unroll
                for (int j = 0; j < 4; ++j) sred[wave][j][lane] = cs[j];
            }
        }
        __syncthreads();    // red/sred ready
        if (tid < 40) {
            float s = red[0][tid] + red[1][tid] + red[2][tid] + red[3][tid];
            atomicAdd(accg + (size_t)b * 40 + tid, s);
        }
        if (do_sum && tid >= 64 && tid < 96) {
            int t2 = tid - 64;
            int j = t2 >> 3, l2 = t2 & 7;
            float4 a0 = sred[0][j][l2], a1 = sred[1][j][l2], a2 = sred[2][j][l2], a3 = sred[3][j][l2];
            float* dst = hsumout + (size_t)b * DD + (j << 5) + (l2 << 2);
            atomicAdd(dst + 0, a0.x + a1.x + a2.x + a3.x);
            atomicAdd(dst + 1, a0.y + a1.y + a2.y + a3.y);
            atomicAdd(dst + 2, a0.z + a1.z + a2.z + a3.z);
            atomicAdd(dst + 3, a0.w + a1.w + a2.w + a3.w);
        }
    }
}

// ---------------------------------------------------------------------------
// Kernel 4: finalize Y1/Y2 and Kabsch alignment (fp64 one-sided Jacobi SVD).
__global__ __launch_bounds__(64) void k_final(const float* __restrict__ accg,
                                              float* __restrict__ out) {
    int b = blockIdx.x;
    int tid = threadIdx.x;
    __shared__ float Ys[2][KK][3];
    if (tid < 2 * KK * 3) {
        int p = tid / 30;
        int r = tid % 30;
        int k = r / 3;
        int c = r % 3;
        const float* a = accg + (size_t)(p * NB + b) * 40;
        float val = a[10 + c * 10 + k] / a[k];
        Ys[p][k][c] = val;
        out[((size_t)(b * 3 + p) * KK + k) * 3 + c] = val;
    }
    __syncthreads();
    if (tid == 0) {
        double P[KK][3], Q[KK][3];
        double c1[3] = {0, 0, 0}, c2[3] = {0, 0, 0};
        for (int i = 0; i < KK; ++i)
            for (int c = 0; c < 3; ++c) {
                P[i][c] = (double)Ys[0][i][c];
                Q[i][c] = (double)Ys[1][i][c];
                c1[c] += P[i][c];
                c2[c] += Q[i][c];
            }
        for (int c = 0; c < 3; ++c) { c1[c] /= KK; c2[c] /= KK; }
        double A0[3][3];
        for (int a = 0; a < 3; ++a)
            for (int c = 0; c < 3; ++c) {
                double s = 0;
                for (int i = 0; i < KK; ++i) s += (P[i][a] - c1[a]) * (Q[i][c] - c2[c]);
                A0[a][c] = s;
            }
        double Bm[3][3], V[3][3];
        for (int a = 0; a < 3; ++a)
            for (int c = 0; c < 3; ++c) { Bm[a][c] = A0[a][c]; V[a][c] = (a == c) ? 1.0 : 0.0; }
        for (int sweep = 0; sweep < 16; ++sweep)
            for (int p = 0; p < 2; ++p)
                for (int q = p + 1; q < 3; ++q) {
                    double al = 0, be = 0, ga = 0;
                    for (int r = 0; r < 3; ++r) {
                        al += Bm[r][p] * Bm[r][p];
                        be += Bm[r][q] * Bm[r][q];
                        ga += Bm[r][p] * Bm[r][q];
                    }
                    if (fabs(ga) < 1e-300) continue;
                    double zeta = (be - al) / (2.0 * ga);
                    double t = copysign(1.0, zeta) / (fabs(zeta) + sqrt(1.0 + zeta * zeta));
                    double cs = 1.0 / sqrt(1.0 + t * t);
                    double sn = cs * t;
                    for (int r = 0; r < 3; ++r) {
                        double bp = Bm[r][p], bq = Bm[r][q];
                        Bm[r][p] = cs * bp - sn * bq;
                        Bm[r][q] = sn * bp + cs * bq;
                        double vp = V[r][p], vq = V[r][q];
                        V[r][p] = cs * vp - sn * vq;
                        V[r][q] = sn * vp + cs * vq;
                    }
                }
        double sig[3];
        for (int j = 0; j < 3; ++j) {
            sig[j] = sqrt(Bm[0][j] * Bm[0][j] + Bm[1][j] * Bm[1][j] + Bm[2][j] * Bm[2][j]);
            if (sig[j] < 1e-300) sig[j] = 1e-300;
        }
        int jmin = 0;
        if (sig[1] < sig[jmin]) jmin = 1;
        if (sig[2] < sig[jmin]) jmin = 2;
        double det = A0[0][0] * (A0[1][1] * A0[2][2] - A0[1][2] * A0[2][1])
                   - A0[0][1] * (A0[1][0] * A0[2][2] - A0[1][2] * A0[2][0])
                   + A0[0][2] * (A0[1][0] * A0[2][1] - A0[1][1] * A0[2][0]);
        double sgn = (det >= 0.0) ? 1.0 : -1.0;
        double R[3][3];
        for (int a = 0; a < 3; ++a)
            for (int c = 0; c < 3; ++c) {
                double s = 0;
                for (int j = 0; j < 3; ++j) {
                    double dj = (j == jmin) ? sgn : 1.0;
                    s += dj * (Bm[a][j] / sig[j]) * V[c][j];
                }
                R[a][c] = s;
            }
        for (int i = 0; i < KK; ++i)
            for (int c = 0; c < 3; ++c) {
                double s = c2[c];
                for (int a = 0; a < 3; ++a) s += (P[i][a] - c1[a]) * R[a][c];
                out[((size_t)(b * 3 + 2) * KK + i) * 3 + c] = (float)s;
            }
    }
}

// ---------------------------------------------------------------------------
extern "C" void kernel_launch(void* const* d_in, const int* in_sizes, int n_in,
                              void* d_out, int out_size, void* d_ws, size_t ws_size,
                              hipStream_t stream) {
    const float* H1 = (const float*)d_in[0];
    const float* H2 = (const float*)d_in[1];
    const float* X1 = (const float*)d_in[2];
    const float* X2 = (const float*)d_in[3];
    const float* W1 = (const float*)d_in[4];
    const float* W2 = (const float*)d_in[5];
    float* out = (float*)d_out;
    float* ws = (float*)d_ws;
    float* hsum = ws;              // 4096 floats
    float* v    = ws + 4096;       // 40960 floats
    float* accg = ws + 45056;      // 1280 floats

    hipMemsetAsync(d_ws, 0, WS_FLOATS * sizeof(float), stream);
    // H2 pass (means only)
    hipLaunchKernelGGL(k_mean2, dim3(1024), dim3(256), 0, stream, H2, hsum);
    // v1 = W1 . mean(H2)
    hipLaunchKernelGGL(k_v, dim3(160), dim3(128), 0, stream, W1, W2, hsum, v, 0);
    // H1 pass: scores for path 1 AND H1 column sums (fused)
    hipLaunchKernelGGL(k_pass, dim3(512), dim3(256), 0, stream,
                       H1, X1, v, accg, hsum, 1);
    // v2 = W2 . mean(H1)
    hipLaunchKernelGGL(k_v, dim3(160), dim3(128), 0, stream, W1, W2, hsum, v, 1);
    // H2 pass: scores for path 2
    hipLaunchKernelGGL(k_pass, dim3(512), dim3(256), 0, stream,
                       H2, X2, v + (size_t)NB * KK * DD, accg + (size_t)NB * 40, hsum, 0);
    hipLaunchKernelGGL(k_final, dim3(16), dim3(64), 0, stream, accg, out);
}

// Round 4
// 400.634 us; speedup vs baseline: 1.0014x; 1.0014x over previous
//
#include <hip/hip_runtime.h>
#include <math.h>

#define NB 16
#define NN 16384
#define DD 128
#define KK 10

// ws layout (floats):
//   hsum : [2][NB][DD]      @0      4096   (plane 0 = sum over H1 rows, plane 1 = H2)
//   v    : [2][NB][KK][DD]  @4096   40960  (scale folded in: 1/(N*sqrt(d)))
//   accg : [2][NB][40]      @45056  1280   ([k]=SE, [10+k]=Yx, [20+k]=Yy, [30+k]=Yz)
#define WS_FLOATS 46336

// Cohort-marching geometry: 2048 blocks = 16 batches x 128 blocks.
// A batch's 128-block cohort sweeps its 8-MB plane in 8 lockstep strides of
// 2048 rows -> DRAM sees 16 long sequential streams (row-buffer friendly)
// instead of ~1360 scattered 64-KB bursts (round 1-3: ~2.5 TB/s, ~40% eff).
// Thread layout: 16 lanes per row, 2 float4 per thread (cols c0 and c0+16).

// ---------------------------------------------------------------------------
// Kernel 1: column sums of H2 (H1's sums come fused from its score pass).
__global__ __launch_bounds__(256) void k_mean2(const float* __restrict__ H2,
                                               float* __restrict__ hsum) {
    int tid = threadIdx.x, b = blockIdx.x;
    int batch = b >> 7, sub = b & 127;
    int c0 = tid & 15;
    int rofs = sub * 16 + (tid >> 4);
    const float4* H4 = (const float4*)H2 + (size_t)batch * (NN * (DD / 4));

    float4 a0 = make_float4(0.f, 0.f, 0.f, 0.f), a1 = a0;
    float4 h0 = H4[(size_t)rofs * 32 + c0];
    float4 h1 = H4[(size_t)rofs * 32 + c0 + 16];
#pragma unroll
    for (int s = 0; s < 8; ++s) {
        float4 g0, g1;
        if (s < 7) {
            int rn = (s + 1) * 2048 + rofs;
            g0 = H4[(size_t)rn * 32 + c0];
            g1 = H4[(size_t)rn * 32 + c0 + 16];
        } else {
            g0 = make_float4(0.f, 0.f, 0.f, 0.f); g1 = g0;
        }
        a0.x += h0.x; a0.y += h0.y; a0.z += h0.z; a0.w += h0.w;
        a1.x += h1.x; a1.y += h1.y; a1.z += h1.z; a1.w += h1.w;
        h0 = g0; h1 = g1;
    }
    // reduce across the 4 lanes sharing c0 (l, l+16, l+32, l+48)
    a0.x += __shfl_xor(a0.x, 16); a0.x += __shfl_xor(a0.x, 32);
    a0.y += __shfl_xor(a0.y, 16); a0.y += __shfl_xor(a0.y, 32);
    a0.z += __shfl_xor(a0.z, 16); a0.z += __shfl_xor(a0.z, 32);
    a0.w += __shfl_xor(a0.w, 16); a0.w += __shfl_xor(a0.w, 32);
    a1.x += __shfl_xor(a1.x, 16); a1.x += __shfl_xor(a1.x, 32);
    a1.y += __shfl_xor(a1.y, 16); a1.y += __shfl_xor(a1.y, 32);
    a1.z += __shfl_xor(a1.z, 16); a1.z += __shfl_xor(a1.z, 32);
    a1.w += __shfl_xor(a1.w, 16); a1.w += __shfl_xor(a1.w, 32);

    __shared__ float4 cred[4][32];
    int wave = tid >> 6, lane = tid & 63;
    if (lane < 16) {
        cred[wave][lane] = a0;
        cred[wave][lane + 16] = a1;
    }
    __syncthreads();
    if (tid < 32) {
        float4 s0 = cred[0][tid], s1 = cred[1][tid], s2 = cred[2][tid], s3 = cred[3][tid];
        float* dst = hsum + (size_t)(NB + batch) * DD + tid * 4;
        atomicAdd(dst + 0, s0.x + s1.x + s2.x + s3.x);
        atomicAdd(dst + 1, s0.y + s1.y + s2.y + s3.y);
        atomicAdd(dst + 2, s0.z + s1.z + s2.z + s3.z);
        atomicAdd(dst + 3, s0.w + s1.w + s2.w + s3.w);
    }
}

// ---------------------------------------------------------------------------
// Kernel 2: v[p][b][k][d] = scale * sum_e W[k][d][e] * hsum[1-p][b][e]
__global__ __launch_bounds__(128) void k_v(const float* __restrict__ W1,
                                           const float* __restrict__ W2,
                                           const float* __restrict__ hsum,
                                           float* __restrict__ v, int p) {
    int bi = blockIdx.x;
    int b = bi / 10;
    int k = bi % 10;
    const float* W = (p ? W2 : W1) + (size_t)k * DD * DD;
    const float* hb = hsum + (size_t)((1 - p) * NB + b) * DD;
    __shared__ float4 h_s[32];
    int tid = threadIdx.x;
    if (tid < 32) h_s[tid] = ((const float4*)hb)[tid];
    __syncthreads();
    const float4* Wrow = (const float4*)(W + (size_t)tid * DD);
    float acc = 0.f;
#pragma unroll 8
    for (int e4 = 0; e4 < 32; ++e4) {
        float4 w4 = Wrow[e4];
        float4 h4 = h_s[e4];
        acc += w4.x * h4.x + w4.y * h4.y + w4.z * h4.z + w4.w * h4.w;
    }
    const float SCALE = (float)(1.0 / (16384.0 * 11.313708498984761));  // 1/(N*sqrt(128))
    v[((size_t)(p * NB + b) * KK + k) * DD + tid] = acc * SCALE;
}

// ---------------------------------------------------------------------------
// Kernel 3: score pass (exp-scores + weighted-X sums; optional fused col-sums).
// v held in registers (20 f4/thread) — no LDS amplification.
__global__ __launch_bounds__(256) void k_pass(const float* __restrict__ H,
                                              const float* __restrict__ X,
                                              const float* __restrict__ v,
                                              float* __restrict__ accg,
                                              float* __restrict__ hsumout,
                                              int do_sum) {
    int tid = threadIdx.x, b = blockIdx.x;
    int batch = b >> 7, sub = b & 127;
    int c0 = tid & 15;
    int rofs = sub * 16 + (tid >> 4);
    const float4* H4 = (const float4*)H + (size_t)batch * (NN * (DD / 4));
    const float* Xb = X + (size_t)batch * NN * 3;
    const float4* v4 = (const float4*)(v + (size_t)batch * KK * DD);

    float4 va[KK], vb[KK];
#pragma unroll
    for (int k = 0; k < KK; ++k) {
        va[k] = v4[k * 32 + c0];
        vb[k] = v4[k * 32 + c0 + 16];
    }

    float pSE[KK], pY0[KK], pY1[KK], pY2[KK];
#pragma unroll
    for (int k = 0; k < KK; ++k) { pSE[k] = 0.f; pY0[k] = 0.f; pY1[k] = 0.f; pY2[k] = 0.f; }
    float4 cs0 = make_float4(0.f, 0.f, 0.f, 0.f), cs1 = cs0;

    float4 h0 = H4[(size_t)rofs * 32 + c0];
    float4 h1 = H4[(size_t)rofs * 32 + c0 + 16];
    float x0 = Xb[rofs * 3 + 0], x1 = Xb[rofs * 3 + 1], x2 = Xb[rofs * 3 + 2];

#pragma unroll
    for (int s = 0; s < 8; ++s) {
        float4 g0, g1;
        float y0, y1, y2;
        if (s < 7) {
            int rn = (s + 1) * 2048 + rofs;
            g0 = H4[(size_t)rn * 32 + c0];
            g1 = H4[(size_t)rn * 32 + c0 + 16];
            y0 = Xb[rn * 3 + 0]; y1 = Xb[rn * 3 + 1]; y2 = Xb[rn * 3 + 2];
        } else {
            g0 = make_float4(0.f, 0.f, 0.f, 0.f); g1 = g0;
            y0 = 0.f; y1 = 0.f; y2 = 0.f;
        }
        float sc[KK];
#pragma unroll
        for (int k = 0; k < KK; ++k)
            sc[k] = h0.x * va[k].x + h0.y * va[k].y + h0.z * va[k].z + h0.w * va[k].w
                  + h1.x * vb[k].x + h1.y * vb[k].y + h1.z * vb[k].z + h1.w * vb[k].w;
        // reduce the 128-dot across the 16 lanes of the row
#pragma unroll
        for (int k = 0; k < KK; ++k) {
            sc[k] += __shfl_xor(sc[k], 1);
            sc[k] += __shfl_xor(sc[k], 2);
            sc[k] += __shfl_xor(sc[k], 4);
            sc[k] += __shfl_xor(sc[k], 8);
        }
        // |s| <~ 0.3 -> exp without max-subtraction is exact softmax semantics.
        // Only one lane per row accumulates (16 lanes hold identical sums).
        if (c0 == 0) {
#pragma unroll
            for (int k = 0; k < KK; ++k) {
                float e = __expf(sc[k]);
                pSE[k] += e;
                pY0[k] += e * x0;
                pY1[k] += e * x1;
                pY2[k] += e * x2;
            }
        }
        if (do_sum) {
            cs0.x += h0.x; cs0.y += h0.y; cs0.z += h0.z; cs0.w += h0.w;
            cs1.x += h1.x; cs1.y += h1.y; cs1.z += h1.z; cs1.w += h1.w;
        }
        h0 = g0; h1 = g1; x0 = y0; x1 = y1; x2 = y2;
    }

    // pSE/pY live on lanes 0,16,32,48 -> sum the 4 row-groups of the wave
#pragma unroll
    for (int k = 0; k < KK; ++k) {
        pSE[k] += __shfl_xor(pSE[k], 16); pSE[k] += __shfl_xor(pSE[k], 32);
        pY0[k] += __shfl_xor(pY0[k], 16); pY0[k] += __shfl_xor(pY0[k], 32);
        pY1[k] += __shfl_xor(pY1[k], 16); pY1[k] += __shfl_xor(pY1[k], 32);
        pY2[k] += __shfl_xor(pY2[k], 16); pY2[k] += __shfl_xor(pY2[k], 32);
    }
    __shared__ float red[4][40];
    __shared__ float4 cred[4][32];
    int wave = tid >> 6, lane = tid & 63;
    if (lane == 0) {
#pragma unroll
        for (int k = 0; k < KK; ++k) {
            red[wave][k] = pSE[k];
            red[wave][10 + k] = pY0[k];
            red[wave][20 + k] = pY1[k];
            red[wave][30 + k] = pY2[k];
        }
    }
    if (do_sum) {
        cs0.x += __shfl_xor(cs0.x, 16); cs0.x += __shfl_xor(cs0.x, 32);
        cs0.y += __shfl_xor(cs0.y, 16); cs0.y += __shfl_xor(cs0.y, 32);
        cs0.z += __shfl_xor(cs0.z, 16); cs0.z += __shfl_xor(cs0.z, 32);
        cs0.w += __shfl_xor(cs0.w, 16); cs0.w += __shfl_xor(cs0.w, 32);
        cs1.x += __shfl_xor(cs1.x, 16); cs1.x += __shfl_xor(cs1.x, 32);
        cs1.y += __shfl_xor(cs1.y, 16); cs1.y += __shfl_xor(cs1.y, 32);
        cs1.z += __shfl_xor(cs1.z, 16); cs1.z += __shfl_xor(cs1.z, 32);
        cs1.w += __shfl_xor(cs1.w, 16); cs1.w += __shfl_xor(cs1.w, 32);
        if (lane < 16) {
            cred[wave][lane] = cs0;
            cred[wave][lane + 16] = cs1;
        }
    }
    __syncthreads();
    if (tid < 40) {
        float ssum = red[0][tid] + red[1][tid] + red[2][tid] + red[3][tid];
        atomicAdd(accg + (size_t)batch * 40 + tid, ssum);
    }
    if (do_sum && tid >= 64 && tid < 96) {
        int c = tid - 64;  // f4 column 0..31
        float4 s0 = cred[0][c], s1 = cred[1][c], s2 = cred[2][c], s3 = cred[3][c];
        float* dst = hsumout + (size_t)batch * DD + c * 4;
        atomicAdd(dst + 0, s0.x + s1.x + s2.x + s3.x);
        atomicAdd(dst + 1, s0.y + s1.y + s2.y + s3.y);
        atomicAdd(dst + 2, s0.z + s1.z + s2.z + s3.z);
        atomicAdd(dst + 3, s0.w + s1.w + s2.w + s3.w);
    }
}

// ---------------------------------------------------------------------------
// Kernel 4: finalize Y1/Y2 and Kabsch alignment (fp64 one-sided Jacobi SVD).
__global__ __launch_bounds__(64) void k_final(const float* __restrict__ accg,
                                              float* __restrict__ out) {
    int b = blockIdx.x;
    int tid = threadIdx.x;
    __shared__ float Ys[2][KK][3];
    if (tid < 2 * KK * 3) {
        int p = tid / 30;
        int r = tid % 30;
        int k = r / 3;
        int c = r % 3;
        const float* a = accg + (size_t)(p * NB + b) * 40;
        float val = a[10 + c * 10 + k] / a[k];
        Ys[p][k][c] = val;
        out[((size_t)(b * 3 + p) * KK + k) * 3 + c] = val;
    }
    __syncthreads();
    if (tid == 0) {
        double P[KK][3], Q[KK][3];
        double c1[3] = {0, 0, 0}, c2[3] = {0, 0, 0};
        for (int i = 0; i < KK; ++i)
            for (int c = 0; c < 3; ++c) {
                P[i][c] = (double)Ys[0][i][c];
                Q[i][c] = (double)Ys[1][i][c];
                c1[c] += P[i][c];
                c2[c] += Q[i][c];
            }
        for (int c = 0; c < 3; ++c) { c1[c] /= KK; c2[c] /= KK; }
        double A0[3][3];
        for (int a = 0; a < 3; ++a)
            for (int c = 0; c < 3; ++c) {
                double s = 0;
                for (int i = 0; i < KK; ++i) s += (P[i][a] - c1[a]) * (Q[i][c] - c2[c]);
                A0[a][c] = s;
            }
        double Bm[3][3], V[3][3];
        for (int a = 0; a < 3; ++a)
            for (int c = 0; c < 3; ++c) { Bm[a][c] = A0[a][c]; V[a][c] = (a == c) ? 1.0 : 0.0; }
        for (int sweep = 0; sweep < 16; ++sweep)
            for (int p = 0; p < 2; ++p)
                for (int q = p + 1; q < 3; ++q) {
                    double al = 0, be = 0, ga = 0;
                    for (int r = 0; r < 3; ++r) {
                        al += Bm[r][p] * Bm[r][p];
                        be += Bm[r][q] * Bm[r][q];
                        ga += Bm[r][p] * Bm[r][q];
                    }
                    if (fabs(ga) < 1e-300) continue;
                    double zeta = (be - al) / (2.0 * ga);
                    double t = copysign(1.0, zeta) / (fabs(zeta) + sqrt(1.0 + zeta * zeta));
                    double cs = 1.0 / sqrt(1.0 + t * t);
                    double sn = cs * t;
                    for (int r = 0; r < 3; ++r) {
                        double bp = Bm[r][p], bq = Bm[r][q];
                        Bm[r][p] = cs * bp - sn * bq;
                        Bm[r][q] = sn * bp + cs * bq;
                        double vp = V[r][p], vq = V[r][q];
                        V[r][p] = cs * vp - sn * vq;
                        V[r][q] = sn * vp + cs * vq;
                    }
                }
        double sig[3];
        for (int j = 0; j < 3; ++j) {
            sig[j] = sqrt(Bm[0][j] * Bm[0][j] + Bm[1][j] * Bm[1][j] + Bm[2][j] * Bm[2][j]);
            if (sig[j] < 1e-300) sig[j] = 1e-300;
        }
        int jmin = 0;
        if (sig[1] < sig[jmin]) jmin = 1;
        if (sig[2] < sig[jmin]) jmin = 2;
        double det = A0[0][0] * (A0[1][1] * A0[2][2] - A0[1][2] * A0[2][1])
                   - A0[0][1] * (A0[1][0] * A0[2][2] - A0[1][2] * A0[2][0])
                   + A0[0][2] * (A0[1][0] * A0[2][1] - A0[1][1] * A0[2][0]);
        double sgn = (det >= 0.0) ? 1.0 : -1.0;
        double R[3][3];
        for (int a = 0; a < 3; ++a)
            for (int c = 0; c < 3; ++c) {
                double s = 0;
                for (int j = 0; j < 3; ++j) {
                    double dj = (j == jmin) ? sgn : 1.0;
                    s += dj * (Bm[a][j] / sig[j]) * V[c][j];
                }
                R[a][c] = s;
            }
        for (int i = 0; i < KK; ++i)
            for (int c = 0; c < 3; ++c) {
                double s = c2[c];
                for (int a = 0; a < 3; ++a) s += (P[i][a] - c1[a]) * R[a][c];
                out[((size_t)(b * 3 + 2) * KK + i) * 3 + c] = (float)s;
            }
    }
}

// ---------------------------------------------------------------------------
extern "C" void kernel_launch(void* const* d_in, const int* in_sizes, int n_in,
                              void* d_out, int out_size, void* d_ws, size_t ws_size,
                              hipStream_t stream) {
    const float* H1 = (const float*)d_in[0];
    const float* H2 = (const float*)d_in[1];
    const float* X1 = (const float*)d_in[2];
    const float* X2 = (const float*)d_in[3];
    const float* W1 = (const float*)d_in[4];
    const float* W2 = (const float*)d_in[5];
    float* out = (float*)d_out;
    float* ws = (float*)d_ws;
    float* hsum = ws;              // 4096 floats
    float* v    = ws + 4096;       // 40960 floats
    float* accg = ws + 45056;      // 1280 floats

    hipMemsetAsync(d_ws, 0, WS_FLOATS * sizeof(float), stream);
    // Sweep 1: H2 column sums (warms L3 for sweep 3)
    hipLaunchKernelGGL(k_mean2, dim3(2048), dim3(256), 0, stream, H2, hsum);
    hipLaunchKernelGGL(k_v, dim3(160), dim3(128), 0, stream, W1, W2, hsum, v, 0);
    // Sweep 2: H1 scores + fused H1 column sums
    hipLaunchKernelGGL(k_pass, dim3(2048), dim3(256), 0, stream,
                       H1, X1, v, accg, hsum, 1);
    hipLaunchKernelGGL(k_v, dim3(160), dim3(128), 0, stream, W1, W2, hsum, v, 1);
    // Sweep 3: H2 scores (L3-warm)
    hipLaunchKernelGGL(k_pass, dim3(2048), dim3(256), 0, stream,
                       H2, X2, v + (size_t)NB * KK * DD, accg + (size_t)NB * 40, hsum, 0);
    hipLaunchKernelGGL(k_final, dim3(16), dim3(64), 0, stream, accg, out);
}